// Round 7
// baseline (911.301 us; speedup 1.0000x reference)
//
#include <hip/hip_runtime.h>

// SlotAttention, algebraically restructured:
//   logits = (LN(slots) @ (Wq^T @ Wk)) . x / 16   (q.bk term dropped: softmax-invariant)
//   updates = softmax-weighted-avg(x) @ Wv^T + bv  (attn rows sum to 1)
// R5-R10: five attn inner-loop structures all FLAT (683+-16us) -> kernel-internal
//   structure exonerated. R8: fixed harness overhead ~272us (2592 timed - 2320 mega);
//   our 10 dispatches burn ~410us vs ~150us bottom-up estimate -> suspect is
//   inter-dispatch cost (launch gaps + 1024-block -> 32-block tail-drain x3).
// R11: dispatch fusion WITHOUT cooperative launch (graph-capture-safe):
//   - k_upd fused into k_attn via last-arrival atomics: per-bb counter (u>>5 maps
//     exactly onto upd block bb's 32 producer units); release = syncthreads +
//     threadfence + device atomicAdd; acquire = threadfence + syncthreads. No
//     spinning -> no deadlock regardless of scheduling. Counters accumulate:
//     winner condition old == 32*it+31; zeroed once in k_qk0.
//   - k_wqk + k_conv + bzr fused into one heterogeneous k_prep (1411 blocks).
//   10 -> 5 dispatches; each iteration is ONE dispatch.

constexpr int Bn = 64;    // batch
constexpr int Nn = 4096;  // inputs per batch
constexpr int Dd = 256;   // feature dim (== IN_D)
constexpr int Ss = 8;     // slots
constexpr int CH = 16;    // N-chunks per batch for attention
constexpr float EPSF = 1e-5f;

#define DEV __device__ __forceinline__

using short8 = __attribute__((ext_vector_type(8))) short;
using f32x4 = __attribute__((ext_vector_type(4))) float;
union U8 { short8 s; uint4 u; };

DEV unsigned bfpack2(float lo, float hi) {
  unsigned ul = __float_as_uint(lo), uh = __float_as_uint(hi);
  ul = (ul + 0x7FFFu + ((ul >> 16) & 1u)) >> 16;         // RNE to bf16
  uh = (uh + 0x7FFFu + ((uh >> 16) & 1u)) & 0xFFFF0000u;
  return ul | uh;
}
DEV unsigned short bf16r(float x) {
  unsigned u = __float_as_uint(x);
  u = (u + 0x7FFFu + ((u >> 16) & 1u)) >> 16;
  return (unsigned short)u;
}
DEV float rsum32(float v) {  // sum within each 32-lane half of a wave
  v += __shfl_xor(v, 1); v += __shfl_xor(v, 2); v += __shfl_xor(v, 4);
  v += __shfl_xor(v, 8); v += __shfl_xor(v, 16);
  return v;
}
DEV float sigm(float x) { return 1.f / (1.f + __expf(-x)); }

// ---- MFMA tile helpers: C[row=quad*4+r][col=t*16+m16] = sum_k A[row][k] W[col][k] + b
template <int NK>
DEV void load_af(short8* a, const unsigned short* base, int lda, int m16, int quad) {
  const unsigned short* p = base + m16 * lda + quad * 8;
#pragma unroll
  for (int kk = 0; kk < NK; ++kk) a[kk] = *(const short8*)(p + kk * 32);
}
template <int NK>
DEV f32x4 gemm_tile(const short8* a, const unsigned short* wr, float binit) {
  f32x4 acc = {binit, binit, binit, binit};
#pragma unroll
  for (int kk = 0; kk < NK; ++kk) {
    short8 b = *(const short8*)(wr + kk * 32);
    acc = __builtin_amdgcn_mfma_f32_16x16x32_bf16(a[kk], b, acc, 0, 0, 0);
  }
  return acc;
}

// LayerNorm over one 256-row held 8-per-thread by 32 lanes; writes bf16 packed out.
DEV void ln_row8(const float* x, const float* g, const float* b, int d0,
                 unsigned short* dst) {
  float s = x[0] + x[1] + x[2] + x[3] + x[4] + x[5] + x[6] + x[7];
  float mu = rsum32(s) * (1.f / 256.f);
  float q = 0.f;
#pragma unroll
  for (int j = 0; j < 8; ++j) { float d = x[j] - mu; q += d * d; }
  float rs = rsqrtf(rsum32(q) * (1.f / 256.f) + EPSF);
  float o[8];
#pragma unroll
  for (int j = 0; j < 8; ++j) o[j] = (x[j] - mu) * rs * g[d0 + j] + b[d0 + j];
  uint4 w;
  w.x = bfpack2(o[0], o[1]); w.y = bfpack2(o[2], o[3]);
  w.z = bfpack2(o[4], o[5]); w.w = bfpack2(o[6], o[7]);
  *(uint4*)dst = w;
}

// ================= device bodies (verified in R8/R9 mega, end-to-end pass) ========

template <bool FIRST>
DEV void ld_chunk_t(const float* __restrict__ xin, unsigned* __restrict__ xbf,
                    size_t nbase, int tid, uint4* pr) {
#pragma unroll
  for (int i = 0; i < 8; ++i) {
    int flat = i * 256 + tid, n = flat >> 5, od = flat & 31;
    if (FIRST) {
      const float4* src = (const float4*)(xin + (nbase + n) * 256 + od * 8);
      float4 v0 = src[0], v1 = src[1];
      uint4 o;
      o.x = bfpack2(v0.x, v0.y); o.y = bfpack2(v0.z, v0.w);
      o.z = bfpack2(v1.x, v1.y); o.w = bfpack2(v1.z, v1.w);
      ((uint4*)xbf)[(nbase + n) * 32 + od] = o;
      pr[i] = o;
    } else {
      pr[i] = ((const uint4*)xbf)[(nbase + n) * 32 + od];
    }
  }
}

template <bool FIRST>
DEV void attn_unit(const float* __restrict__ xin, unsigned* __restrict__ xbf,
                   const float* __restrict__ qk, float* __restrict__ pl,
                   float* __restrict__ pu, unsigned* xt, unsigned* pp,
                   float (*lred)[16], int u, int tid) {
  const int lane = tid & 63, wave = tid >> 6;
  const int m16 = lane & 15, quad = lane >> 4;
  const int b = u >> 4, c = u & 15;
  const int pb = u * 8;
  const unsigned psel = (m16 & 1) ? 0x07060302u : 0x05040100u;

  short8 aq[8];
  {
    const float* qrow = qk + (size_t)(b * 8 + (m16 & 7)) * 256 + quad * 8;
#pragma unroll
    for (int kk = 0; kk < 8; ++kk) {
      U8 f;
      float4 q0 = *(const float4*)(qrow + kk * 32);
      float4 q1 = *(const float4*)(qrow + kk * 32 + 4);
      f.u.x = bfpack2(q0.x, q0.y); f.u.y = bfpack2(q0.z, q0.w);
      f.u.z = bfpack2(q1.x, q1.y); f.u.w = bfpack2(q1.z, q1.w);
      if (m16 >= 8) { f.u.x = 0u; f.u.y = 0u; f.u.z = 0u; f.u.w = 0u; }
      aq[kk] = f.s;
    }
  }
  float lacc[4] = {0.f, 0.f, 0.f, 0.f};
  f32x4 acc[4];
#pragma unroll
  for (int t = 0; t < 4; ++t) acc[t] = (f32x4){0.f, 0.f, 0.f, 0.f};
  const int d0w = wave * 64;

  uint4 pr[8];
  const size_t nb0 = (size_t)b * Nn + (size_t)c * 256;
  ld_chunk_t<FIRST>(xin, xbf, nb0, tid, pr);

  for (int ch = 0; ch < 4; ++ch) {
#pragma unroll
    for (int i = 0; i < 8; ++i) {
      int flat = i * 256 + tid, n = flat >> 5, od = flat & 31, rb = od * 4;
      xt[(rb + 0) * 65 + n] = pr[i].x;
      xt[(rb + 1) * 65 + n] = pr[i].y;
      xt[(rb + 2) * 65 + n] = pr[i].z;
      xt[(rb + 3) * 65 + n] = pr[i].w;
    }
    __syncthreads();
    if (ch + 1 < 4)
      ld_chunk_t<FIRST>(xin, xbf, nb0 + (size_t)(ch + 1) * 64, tid, pr);
    // phase A: wave w computes n-tile nt=w
    {
      const int nt = wave;
      f32x4 pacc = (f32x4){0.f, 0.f, 0.f, 0.f};
#pragma unroll
      for (int kk = 0; kk < 8; ++kk) {
        int base = (kk * 16 + quad * 4) * 65 + nt * 16 + m16;
        U8 bf;
        bf.u.x = xt[base]; bf.u.y = xt[base + 65];
        bf.u.z = xt[base + 130]; bf.u.w = xt[base + 195];
        pacc = __builtin_amdgcn_mfma_f32_16x16x32_bf16(aq[kk], bf.s, pacc, 0, 0, 0);
      }
      const int xrow = nt * 16 + m16;
      unsigned short* pps = (unsigned short*)pp;
#pragma unroll
      for (int r = 0; r < 4; ++r) {
        float p = __expf(pacc[r]);  // |logit| small: no max-shift needed
        lacc[r] += p;
        pps[((xrow >> 1) * 17 + quad * 4 + r) * 2 + (xrow & 1)] = bf16r(p);
      }
    }
    __syncthreads();
    // phase B: wave owns 64 d-cols
#pragma unroll
    for (int nh = 0; nh < 2; ++nh) {
      U8 bp;
      bp.u.x = pp[(nh * 16 + quad * 4 + 0) * 17 + m16];
      bp.u.y = pp[(nh * 16 + quad * 4 + 1) * 17 + m16];
      bp.u.z = pp[(nh * 16 + quad * 4 + 2) * 17 + m16];
      bp.u.w = pp[(nh * 16 + quad * 4 + 3) * 17 + m16];
#pragma unroll
      for (int t = 0; t < 4; ++t) {
        int d = d0w + t * 16 + m16;
        const unsigned* xr = xt + (d >> 1) * 65 + nh * 32 + quad * 8;
        unsigned u0 = xr[0], u1 = xr[1], u2 = xr[2], u3 = xr[3];
        unsigned u4 = xr[4], u5 = xr[5], u6 = xr[6], u7 = xr[7];
        U8 af;
        af.u.x = __builtin_amdgcn_perm(u1, u0, psel);
        af.u.y = __builtin_amdgcn_perm(u3, u2, psel);
        af.u.z = __builtin_amdgcn_perm(u5, u4, psel);
        af.u.w = __builtin_amdgcn_perm(u7, u6, psel);
        acc[t] = __builtin_amdgcn_mfma_f32_16x16x32_bf16(af.s, bp.s, acc[t], 0, 0, 0);
      }
    }
    __syncthreads();
  }
  if (m16 < 8) {
#pragma unroll
    for (int t = 0; t < 4; ++t)
#pragma unroll
      for (int r = 0; r < 4; ++r)
        pu[(size_t)(pb + m16) * 256 + d0w + t * 16 + quad * 4 + r] = acc[t][r];
  }
#pragma unroll
  for (int r = 0; r < 4; ++r) {
    float v = lacc[r];
    v += __shfl_xor(v, 1); v += __shfl_xor(v, 2);
    v += __shfl_xor(v, 4); v += __shfl_xor(v, 8);
    if (m16 == 0) lred[wave][quad * 4 + r] = v;
  }
  __syncthreads();
  if (tid < 8)
    pl[pb + tid] = lred[0][tid] + lred[1][tid] + lred[2][tid] + lred[3][tid];
}

// ---- 256-thread slot-update body: 16 rows, 4 tiles/wave, s1 in-place in sp,
//      LN buffer aliased onto cat cols [256,520) ----
DEV void upd_body256(
    const float* __restrict__ pl, const float* __restrict__ pu,
    const unsigned short* __restrict__ Wv_b, const float* __restrict__ bv,
    const unsigned short* __restrict__ Wzr_b, const float* __restrict__ bzr,
    const unsigned short* __restrict__ Win_b, const float* __restrict__ bin,
    const unsigned short* __restrict__ Whn_b, const float* __restrict__ bhn,
    const unsigned short* __restrict__ W1_b, const float* __restrict__ b1,
    const unsigned short* __restrict__ W2_b, const float* __restrict__ b2,
    const float* __restrict__ gml, const float* __restrict__ bml,
    const float* __restrict__ gsl, const float* __restrict__ bsl,
    const unsigned short* __restrict__ Wqk_b, const float* __restrict__ bqk,
    float* __restrict__ slots, float* __restrict__ qk, float* __restrict__ dout,
    unsigned short* cat, float* sp, int bb, int tid) {
  unsigned short* lnbp = cat + 256;  // per-row cols [256,520), stride 520
  const int lane = tid & 63, wave4 = tid >> 6;
  const int m16 = lane & 15, quad = lane >> 4;
  const int row8 = tid >> 5, l32 = tid & 31, d0 = l32 * 8;
  // step 1: combine
#pragma unroll
  for (int r2 = 0; r2 < 2; ++r2) {
    const int row = row8 + 8 * r2;
    const int bat = 2 * bb + (row >> 3), sl = row & 7;
    float L = 0.f;
#pragma unroll
    for (int cc = 0; cc < 16; ++cc) L += pl[(bat * 16 + cc) * 8 + sl];
    float li = 1.f / L;
    float a[8] = {0.f, 0.f, 0.f, 0.f, 0.f, 0.f, 0.f, 0.f};
    for (int cc = 0; cc < 16; ++cc) {
      const float* pp_ = pu + ((size_t)(bat * 16 + cc) * 8 + sl) * 256 + d0;
      float4 v0 = *(const float4*)pp_, v1 = *(const float4*)(pp_ + 4);
      a[0] += v0.x; a[1] += v0.y; a[2] += v0.z; a[3] += v0.w;
      a[4] += v1.x; a[5] += v1.y; a[6] += v1.z; a[7] += v1.w;
    }
    uint4 o;
    o.x = bfpack2(a[0] * li, a[1] * li); o.y = bfpack2(a[2] * li, a[3] * li);
    o.z = bfpack2(a[4] * li, a[5] * li); o.w = bfpack2(a[6] * li, a[7] * li);
    *(uint4*)(cat + row * 520 + d0) = o;
    const float* sp_ = slots + (size_t)(bb * 16 + row) * 256 + d0;
    float4 h0 = *(const float4*)sp_, h1 = *(const float4*)(sp_ + 4);
    *(float4*)(sp + row * 260 + d0) = h0;
    *(float4*)(sp + row * 260 + d0 + 4) = h1;
    uint4 hb;
    hb.x = bfpack2(h0.x, h0.y); hb.y = bfpack2(h0.z, h0.w);
    hb.z = bfpack2(h1.x, h1.y); hb.w = bfpack2(h1.z, h1.w);
    *(uint4*)(cat + row * 520 + 256 + d0) = hb;
  }
  __syncthreads();
  // step 2: updates = u' @ Wv^T + bv
  short8 afr[16];
  load_af<8>(afr, cat, 520, m16, quad);
  f32x4 accv[4];
#pragma unroll
  for (int i = 0; i < 4; ++i) {
    int t = wave4 + 4 * i;
    accv[i] = gemm_tile<8>(afr, Wv_b + (size_t)(t * 16 + m16) * 256 + quad * 8,
                           bv[t * 16 + m16]);
  }
  __syncthreads();
#pragma unroll
  for (int i = 0; i < 4; ++i) {
    int t = wave4 + 4 * i;
#pragma unroll
    for (int r = 0; r < 4; ++r)
      cat[(quad * 4 + r) * 520 + t * 16 + m16] = bf16r(accv[i][r]);
  }
  __syncthreads();
  // steps 3+4 merged per-tile: gates transient, slots1 written in-place into sp
  load_af<16>(afr, cat, 520, m16, quad);
#pragma unroll
  for (int i = 0; i < 4; ++i) {
    int t = wave4 + 4 * i, col = t * 16 + m16;
    f32x4 ar = gemm_tile<16>(afr, Wzr_b + (size_t)(t * 16 + m16) * 512 + quad * 8,
                             bzr[t * 16 + m16]);
    f32x4 az = gemm_tile<16>(afr, Wzr_b + (size_t)((t + 16) * 16 + m16) * 512 + quad * 8,
                             bzr[(t + 16) * 16 + m16]);
    f32x4 ain = gemm_tile<8>(afr, Win_b + (size_t)(t * 16 + m16) * 256 + quad * 8,
                             bin[col]);
    f32x4 ahn = gemm_tile<8>(afr + 8, Whn_b + (size_t)(t * 16 + m16) * 256 + quad * 8,
                             bhn[col]);
#pragma unroll
    for (int r = 0; r < 4; ++r) {
      int rw = quad * 4 + r;
      float rrv = sigm(ar[r]), zzv = sigm(az[r]);
      float nin = ain[r] + rrv * ahn[r];
      float nn = 1.f - 2.f / (__expf(2.f * nin) + 1.f);  // tanh
      float hpc = sp[rw * 260 + col];
      sp[rw * 260 + col] = hpc + (1.f - zzv) * nn + zzv * hpc;  // prev + h_new
    }
  }
  __syncthreads();
  // step 5: LN_mlp(slots1) -> lnbp
#pragma unroll
  for (int r2 = 0; r2 < 2; ++r2) {
    int row = row8 + 8 * r2;
    const float* s1r = sp + row * 260 + d0;
    float4 v0 = *(const float4*)s1r, v1 = *(const float4*)(s1r + 4);
    float x[8] = {v0.x, v0.y, v0.z, v0.w, v1.x, v1.y, v1.z, v1.w};
    ln_row8(x, gml, bml, d0, lnbp + row * 520 + d0);
  }
  __syncthreads();
  // step 6: hid = relu(LN_mlp @ W1^T + b1) -> cat[:,0:256)
  load_af<8>(afr, lnbp, 520, m16, quad);
#pragma unroll
  for (int i = 0; i < 4; ++i) {
    int t = wave4 + 4 * i;
    f32x4 acc = gemm_tile<8>(afr, W1_b + (size_t)(t * 16 + m16) * 256 + quad * 8,
                             b1[t * 16 + m16]);
#pragma unroll
    for (int r = 0; r < 4; ++r)
      cat[(quad * 4 + r) * 520 + t * 16 + m16] = bf16r(fmaxf(acc[r], 0.f));
  }
  __syncthreads();
  // step 7: slots2 = slots1 + hid @ W2^T + b2 (in-place into sp) + global
  load_af<8>(afr, cat, 520, m16, quad);
#pragma unroll
  for (int i = 0; i < 4; ++i) {
    int t = wave4 + 4 * i;
    f32x4 acc = gemm_tile<8>(afr, W2_b + (size_t)(t * 16 + m16) * 256 + quad * 8,
                             b2[t * 16 + m16]);
#pragma unroll
    for (int r = 0; r < 4; ++r) {
      int rw = quad * 4 + r, col = t * 16 + m16;
      float v = acc[r] + sp[rw * 260 + col];
      size_t gi = (size_t)(bb * 16 + rw) * 256 + col;
      slots[gi] = v;
      if (dout) dout[gi] = v;
      sp[rw * 260 + col] = v;
    }
  }
  __syncthreads();
  // step 8: LN_slots(slots2) -> lnbp
#pragma unroll
  for (int r2 = 0; r2 < 2; ++r2) {
    int row = row8 + 8 * r2;
    const float* spr = sp + row * 260 + d0;
    float4 v0 = *(const float4*)spr, v1 = *(const float4*)(spr + 4);
    float x[8] = {v0.x, v0.y, v0.z, v0.w, v1.x, v1.y, v1.z, v1.w};
    ln_row8(x, gsl, bsl, d0, lnbp + row * 520 + d0);
  }
  __syncthreads();
  // step 9: q' = (LN_slots @ WqkT + bqk)/16
  load_af<8>(afr, lnbp, 520, m16, quad);
#pragma unroll
  for (int i = 0; i < 4; ++i) {
    int t = wave4 + 4 * i;
    f32x4 acc = gemm_tile<8>(afr, Wqk_b + (size_t)(t * 16 + m16) * 256 + quad * 8,
                             bqk[t * 16 + m16]);
#pragma unroll
    for (int r = 0; r < 4; ++r)
      qk[(size_t)(bb * 16 + quad * 4 + r) * 256 + t * 16 + m16] = acc[r] * 0.0625f;
  }
}

// ---- prep unit: u<256 wqk col; u==256 bqk; u>=257 conv chunks ----
DEV void prep_unit(int u, int tid,
                   const float* Wq, const float* Wk, const float* bq,
                   unsigned short* Wqk_b, float* bqk,
                   const float* Wv, const float* Wih, const float* Whh,
                   const float* W1, const float* W2,
                   const float* bih, const float* bhh,
                   unsigned* Wv_b, unsigned* Wzr_b, unsigned* Win_b, unsigned* Whn_b,
                   unsigned* W1_b, unsigned* W2_b, float* bzr) {
  if (u < 256) {
    float acc = 0.f;
    for (int e = 0; e < 256; ++e) acc += Wq[e * 256 + tid] * Wk[e * 256 + u];
    Wqk_b[u * 256 + tid] = bf16r(acc);
  } else if (u == 256) {
    float acc = 0.f;
    for (int e = 0; e < 256; ++e) acc += bq[e] * Wk[e * 256 + tid];
    bqk[tid] = acc;
  } else {
    int cu = u - 257;
    if (cu >= 1152) {
      int i = (cu - 1152) * 256 + tid;
      if (i < 512) bzr[i] = bih[i] + bhh[i];
      return;
    }
    int p = cu * 256 + tid;
    const float* src; unsigned* dst;
    if (p < 32768) { src = Wv + 2 * p; dst = Wv_b + p; }
    else if (p < 163840) {
      int q = p - 32768, row = q >> 8, col = (q & 255) * 2;
      src = (col < 256) ? (Wih + row * 256 + col) : (Whh + row * 256 + col - 256);
      dst = Wzr_b + q;
    }
    else if (p < 196608) { int q = p - 163840; src = Wih + 512 * 256 + 2 * q; dst = Win_b + q; }
    else if (p < 229376) { int q = p - 196608; src = Whh + 512 * 256 + 2 * q; dst = Whn_b + q; }
    else if (p < 262144) { int q = p - 229376; src = W1 + 2 * q; dst = W1_b + q; }
    else { int q = p - 262144; src = W2 + 2 * q; dst = W2_b + q; }
    dst[0] = bfpack2(src[0], src[1]);
  }
}

// ================= kernels =================

__global__ __launch_bounds__(256) void k_prep(
    const float* __restrict__ Wq, const float* __restrict__ Wk,
    const float* __restrict__ bq, unsigned short* __restrict__ Wqk_b,
    float* __restrict__ bqk, const float* __restrict__ Wv,
    const float* __restrict__ Wih, const float* __restrict__ Whh,
    const float* __restrict__ W1, const float* __restrict__ W2,
    const float* __restrict__ bih, const float* __restrict__ bhh,
    unsigned* Wv_b, unsigned* Wzr_b, unsigned* Win_b, unsigned* Whn_b,
    unsigned* W1_b, unsigned* W2_b, float* bzr) {
  prep_unit(blockIdx.x, threadIdx.x, Wq, Wk, bq, Wqk_b, bqk, Wv, Wih, Whh, W1, W2,
            bih, bhh, Wv_b, Wzr_b, Win_b, Whn_b, W1_b, W2_b, bzr);
}

// slots = mu + sigma*noise; q' = (LN(slots)@WqkT + bqk)/16; zero upd counters.
__global__ __launch_bounds__(512) void k_qk0(const float* __restrict__ noise,
                                             const float* __restrict__ s_mu,
                                             const float* __restrict__ s_sg,
                                             const float* __restrict__ gsl,
                                             const float* __restrict__ bsl,
                                             const unsigned short* __restrict__ Wqk_b,
                                             const float* __restrict__ bqk,
                                             float* __restrict__ slots,
                                             float* __restrict__ qk,
                                             int* __restrict__ cnt) {
  __shared__ __align__(16) unsigned short lnb[16 * 264];
  const int tid = threadIdx.x, bb = blockIdx.x;
  if (bb == 0 && tid < 32) cnt[tid] = 0;
  const int lane = tid & 63, wave = tid >> 6;
  const int m16 = lane & 15, quad = lane >> 4;
  const int row = tid >> 5, l32 = tid & 31, d0 = l32 * 8;
  {
    const int grow = bb * 16 + row;            // = b*8 + s
    const int sidx = (grow & 7) * 256 + d0;
    const float* np = noise + (size_t)grow * 256 + d0;
    float4 n0 = *(const float4*)np, n1 = *(const float4*)(np + 4);
    float4 m0 = *(const float4*)(s_mu + sidx), m1 = *(const float4*)(s_mu + sidx + 4);
    float4 g0 = *(const float4*)(s_sg + sidx), g1 = *(const float4*)(s_sg + sidx + 4);
    float x[8] = {m0.x + g0.x * n0.x, m0.y + g0.y * n0.y,
                  m0.z + g0.z * n0.z, m0.w + g0.w * n0.w,
                  m1.x + g1.x * n1.x, m1.y + g1.y * n1.y,
                  m1.z + g1.z * n1.z, m1.w + g1.w * n1.w};
    float* sp_ = slots + (size_t)grow * 256 + d0;
    float4 o0, o1;
    o0.x = x[0]; o0.y = x[1]; o0.z = x[2]; o0.w = x[3];
    o1.x = x[4]; o1.y = x[5]; o1.z = x[6]; o1.w = x[7];
    *(float4*)sp_ = o0; *(float4*)(sp_ + 4) = o1;
    ln_row8(x, gsl, bsl, d0, lnb + row * 264 + d0);
  }
  __syncthreads();
  short8 a8[8];
  load_af<8>(a8, lnb, 264, m16, quad);
#pragma unroll
  for (int i = 0; i < 2; ++i) {
    int t = wave + 8 * i;
    f32x4 acc = gemm_tile<8>(a8, Wqk_b + (size_t)(t * 16 + m16) * 256 + quad * 8,
                             bqk[t * 16 + m16]);
#pragma unroll
    for (int r = 0; r < 4; ++r)
      qk[(size_t)(bb * 16 + quad * 4 + r) * 256 + t * 16 + m16] = acc[r] * 0.0625f;
  }
}

struct IterArgs {
  const float* xin;
  unsigned* xbf;
  float *qk, *pl, *pu;
  int* cnt;
  const unsigned short *Wv_b, *Wzr_b, *Win_b, *Whn_b, *W1_b, *W2_b, *Wqk_b;
  const float *bv, *bzr, *bin, *bhn, *b1, *b2, *gml, *bml, *gsl, *bsl, *bqk;
  float *slots, *out;
};

// One fused iteration: 1024 attn blocks; the last arrival of each 32-unit group
// (per-bb counter) additionally runs that bb's slot-update in the same block.
template <int IT>
__global__ __launch_bounds__(256) void k_attn_f(IterArgs a) {
  __shared__ __align__(16) union SMU {
    struct { unsigned xt[128 * 65]; unsigned pp[32 * 17]; float lred[4][16]; } at;
    struct { unsigned short cat[16 * 520]; float sp[16 * 260]; } up;
  } sm;
  __shared__ int win;
  const int tid = threadIdx.x;
  const int u = (int)blockIdx.y * CH + (int)blockIdx.x;
  const int bb = u >> 5;

  attn_unit<IT == 0>(a.xin, a.xbf, a.qk, a.pl, a.pu, sm.at.xt, sm.at.pp, sm.at.lred,
                     u, tid);
  // release: all this block's pl/pu writes -> visible device-wide before count
  __syncthreads();
  if (tid == 0) {
    __threadfence();
    int old = atomicAdd(&a.cnt[bb], 1);
    win = (old == IT * 32 + 31) ? 1 : 0;
    if (win) __threadfence();  // acquire: producers' writes now visible
  }
  __syncthreads();
  if (win) {
    upd_body256(a.pl, a.pu, a.Wv_b, a.bv, a.Wzr_b, a.bzr, a.Win_b, a.bin, a.Whn_b,
                a.bhn, a.W1_b, a.b1, a.W2_b, a.b2, a.gml, a.bml, a.gsl, a.bsl,
                a.Wqk_b, a.bqk, a.slots, a.qk, (IT == 2) ? a.out : nullptr,
                sm.up.cat, sm.up.sp, bb, tid);
  }
}

// ---------------- launch ----------------
extern "C" void kernel_launch(void* const* d_in, const int* in_sizes, int n_in,
                              void* d_out, int out_size, void* d_ws, size_t ws_size,
                              hipStream_t stream) {
  const float* inputs = (const float*)d_in[0];
  const float* noise = (const float*)d_in[1];
  const float* s_mu = (const float*)d_in[2];
  const float* s_sg = (const float*)d_in[3];
  const float* Wq = (const float*)d_in[4];
  const float* bq = (const float*)d_in[5];
  const float* Wk = (const float*)d_in[6];
  // d_in[7] = bk: unused (softmax-invariant)
  const float* Wv = (const float*)d_in[8];
  const float* bv = (const float*)d_in[9];
  const float* Wih = (const float*)d_in[10];
  const float* bih = (const float*)d_in[11];
  const float* Whh = (const float*)d_in[12];
  const float* bhh = (const float*)d_in[13];
  const float* W1 = (const float*)d_in[14];
  const float* b1 = (const float*)d_in[15];
  const float* W2 = (const float*)d_in[16];
  const float* b2 = (const float*)d_in[17];
  const float* gsl = (const float*)d_in[18];
  const float* bsl = (const float*)d_in[19];
  const float* gml = (const float*)d_in[20];
  const float* bml = (const float*)d_in[21];
  float* out = (float*)d_out;

  char* wsb = (char*)d_ws;
  unsigned* xbf = (unsigned*)wsb;  // bf16 copy of inputs: 128 MiB
  float* fp = (float*)(wsb + (size_t)Bn * Nn * Dd * 2);
  float* slots = fp; fp += Bn * Ss * Dd;
  float* qk = fp;    fp += Bn * Ss * Dd;
  float* bqk = fp;   fp += Dd;
  float* pl = fp;    fp += Bn * CH * Ss;
  float* pu = fp;    fp += Bn * CH * Ss * Dd;
  float* bzr = fp;   fp += 512;
  int* cnt = (int*)fp; fp += 32;
  unsigned short* wb = (unsigned short*)fp;
  unsigned short* Wv_b = wb;  wb += 65536;
  unsigned short* Wzr_b = wb; wb += 262144;
  unsigned short* Win_b = wb; wb += 65536;
  unsigned short* Whn_b = wb; wb += 65536;
  unsigned short* W1_b = wb;  wb += 65536;
  unsigned short* W2_b = wb;  wb += 65536;
  unsigned short* Wqk_b = wb; wb += 65536;
  (void)in_sizes; (void)n_in; (void)out_size; (void)ws_size;

  k_prep<<<dim3(1411), dim3(256), 0, stream>>>(
      Wq, Wk, bq, Wqk_b, bqk, Wv, Wih, Whh, W1, W2, bih, bhh, (unsigned*)Wv_b,
      (unsigned*)Wzr_b, (unsigned*)Win_b, (unsigned*)Whn_b, (unsigned*)W1_b,
      (unsigned*)W2_b, bzr);
  k_qk0<<<dim3(32), dim3(512), 0, stream>>>(noise, s_mu, s_sg, gsl, bsl, Wqk_b, bqk,
                                            slots, qk, cnt);
  IterArgs a;
  a.xin = inputs; a.xbf = xbf; a.qk = qk; a.pl = pl; a.pu = pu; a.cnt = cnt;
  a.Wv_b = Wv_b; a.Wzr_b = Wzr_b; a.Win_b = Win_b; a.Whn_b = Whn_b;
  a.W1_b = W1_b; a.W2_b = W2_b; a.Wqk_b = Wqk_b;
  a.bv = bv; a.bzr = bzr; a.bin = bih + 512; a.bhn = bhh + 512;
  a.b1 = b1; a.b2 = b2; a.gml = gml; a.bml = bml; a.gsl = gsl; a.bsl = bsl;
  a.bqk = bqk; a.slots = slots; a.out = out;
  k_attn_f<0><<<dim3(CH, Bn), dim3(256), 0, stream>>>(a);
  k_attn_f<1><<<dim3(CH, Bn), dim3(256), 0, stream>>>(a);
  k_attn_f<2><<<dim3(CH, Bn), dim3(256), 0, stream>>>(a);
}

// Round 8
// 678.056 us; speedup vs baseline: 1.3440x; 1.3440x over previous
//
#include <hip/hip_runtime.h>

// SlotAttention, algebraically restructured:
//   logits = (LN(slots) @ (Wq^T @ Wk)) . x / 16   (q.bk term dropped: softmax-invariant)
//   updates = softmax-weighted-avg(x) @ Wv^T + bv  (attn rows sum to 1)
// R5-R10: five attn inner-loop structures FLAT (~683). R11 fusion: +75us/iter
//   (spilled upd path), but gave the decomposition: attn ~195-200us/iter (~85%),
//   upd ~10-20us, inter-dispatch gaps ~0. xconv streams at 5.7 TB/s while attn
//   moves 143MB at ~1 TB/s -> attn cost scales with ITS byte volume.
// R12: fp8-e4m3 attention. X/q/P quantized to OCP e4m3 (errors sub-1% by
//   averaging); mfma_f32_16x16x32_fp8_fp8 (same fragment geometry, i64 operands).
//   xbf 128->64 MiB, attn traffic/iter 134->67 MB, load count halved, LDS dual
//   layout (row-major for phase A b64 reads; byte-transposed for phase B via
//   v_perm byte-extract) -> conflict-light. /16 applied post-MFMA (q unscaled).
//   Fusion reverted: standalone k_upd (512thr, R7-verbatim minus 0.0625);
//   k_prep reworked (8 cols/block: 67->8 MB of Wq reads).

constexpr int Bn = 64;    // batch
constexpr int Nn = 4096;  // inputs per batch
constexpr int Dd = 256;   // feature dim (== IN_D)
constexpr int Ss = 8;     // slots
constexpr int CH = 16;    // N-chunks per batch for attention
constexpr float EPSF = 1e-5f;

#define DEV __device__ __forceinline__

using short8 = __attribute__((ext_vector_type(8))) short;
using f32x4 = __attribute__((ext_vector_type(4))) float;
union U8 { short8 s; uint4 u; };
union LL { unsigned u[2]; long long l; };

DEV unsigned bfpack2(float lo, float hi) {
  unsigned ul = __float_as_uint(lo), uh = __float_as_uint(hi);
  ul = (ul + 0x7FFFu + ((ul >> 16) & 1u)) >> 16;         // RNE to bf16
  uh = (uh + 0x7FFFu + ((uh >> 16) & 1u)) & 0xFFFF0000u;
  return ul | uh;
}
DEV unsigned short bf16r(float x) {
  unsigned u = __float_as_uint(x);
  u = (u + 0x7FFFu + ((u >> 16) & 1u)) >> 16;
  return (unsigned short)u;
}
// fp32 -> OCP e4m3fn, RNE, satfinite. bias 7, max 448, denorm step 2^-9.
DEV unsigned f8q(float x) {
  unsigned u = __float_as_uint(x), s = (u >> 24) & 0x80u;
  float a = __uint_as_float(u & 0x7FFFFFFFu);
  if (a >= 448.f) return s | 0x7Eu;
  if (a < 0.015625f) {
    int m = (int)rintf(a * 512.f);
    return s | (unsigned)m;  // m==8 encodes 0x08 = 2^-6 exactly
  }
  unsigned v = (u & 0x7FFFFFFFu) + 0x7FFFFu + ((u >> 20) & 1u);
  unsigned E = (v >> 23) - 120u;
  unsigned M = (v >> 20) & 7u;
  if (E > 15u) return s | 0x7Eu;
  unsigned r = (E << 3) | M;
  if (r > 0x7Eu) r = 0x7Eu;
  return s | r;
}
DEV float rsum32(float v) {  // sum within each 32-lane half of a wave
  v += __shfl_xor(v, 1); v += __shfl_xor(v, 2); v += __shfl_xor(v, 4);
  v += __shfl_xor(v, 8); v += __shfl_xor(v, 16);
  return v;
}
DEV float sigm(float x) { return 1.f / (1.f + __expf(-x)); }

// ---- bf16 MFMA tile helpers (k_upd/k_qk0 path) ----
template <int NK>
DEV void load_af(short8* a, const unsigned short* base, int lda, int m16, int quad) {
  const unsigned short* p = base + m16 * lda + quad * 8;
#pragma unroll
  for (int kk = 0; kk < NK; ++kk) a[kk] = *(const short8*)(p + kk * 32);
}
template <int NK>
DEV f32x4 gemm_tile(const short8* a, const unsigned short* wr, float binit) {
  f32x4 acc = {binit, binit, binit, binit};
#pragma unroll
  for (int kk = 0; kk < NK; ++kk) {
    short8 b = *(const short8*)(wr + kk * 32);
    acc = __builtin_amdgcn_mfma_f32_16x16x32_bf16(a[kk], b, acc, 0, 0, 0);
  }
  return acc;
}

// LayerNorm over one 256-row held 8-per-thread by 32 lanes; writes bf16 packed out.
DEV void ln_row8(const float* x, const float* g, const float* b, int d0,
                 unsigned short* dst) {
  float s = x[0] + x[1] + x[2] + x[3] + x[4] + x[5] + x[6] + x[7];
  float mu = rsum32(s) * (1.f / 256.f);
  float q = 0.f;
#pragma unroll
  for (int j = 0; j < 8; ++j) { float d = x[j] - mu; q += d * d; }
  float rs = rsqrtf(rsum32(q) * (1.f / 256.f) + EPSF);
  float o[8];
#pragma unroll
  for (int j = 0; j < 8; ++j) o[j] = (x[j] - mu) * rs * g[d0 + j] + b[d0 + j];
  uint4 w;
  w.x = bfpack2(o[0], o[1]); w.y = bfpack2(o[2], o[3]);
  w.z = bfpack2(o[4], o[5]); w.w = bfpack2(o[6], o[7]);
  *(uint4*)dst = w;
}

// ---------------- prep: wqk (8 cols/block) + bqk + weight conversion ----------------
__global__ __launch_bounds__(256) void k_prep(
    const float* __restrict__ Wq, const float* __restrict__ Wk,
    const float* __restrict__ bq, unsigned short* __restrict__ Wqk_b,
    float* __restrict__ bqk, const float* __restrict__ Wv,
    const float* __restrict__ Wih, const float* __restrict__ Whh,
    const float* __restrict__ W1, const float* __restrict__ W2,
    const float* __restrict__ bih, const float* __restrict__ bhh,
    unsigned* Wv_b, unsigned* Wzr_b, unsigned* Win_b, unsigned* Whn_b,
    unsigned* W1_b, unsigned* W2_b, float* bzr) {
  const int u = blockIdx.x, tid = threadIdx.x;
  if (u < 32) {  // Wqk_b[c][d] = bf16(sum_e Wq[e][d]*Wk[e][c]), 8 c per block
    const int c0 = u * 8;
    float acc[8] = {0.f, 0.f, 0.f, 0.f, 0.f, 0.f, 0.f, 0.f};
    for (int e = 0; e < 256; ++e) {
      float wq = Wq[e * 256 + tid];
      const float* wk = Wk + e * 256 + c0;
#pragma unroll
      for (int j = 0; j < 8; ++j) acc[j] += wq * wk[j];
    }
#pragma unroll
    for (int j = 0; j < 8; ++j) Wqk_b[(c0 + j) * 256 + tid] = bf16r(acc[j]);
  } else if (u == 32) {
    float acc = 0.f;
    for (int e = 0; e < 256; ++e) acc += bq[e] * Wk[e * 256 + tid];
    bqk[tid] = acc;
  } else {
    int cu = u - 33;
    if (cu >= 1152) {
      int i = (cu - 1152) * 256 + tid;
      if (i < 512) bzr[i] = bih[i] + bhh[i];
      return;
    }
    int p = cu * 256 + tid;  // bf16-pair index
    const float* src; unsigned* dst;
    if (p < 32768) { src = Wv + 2 * p; dst = Wv_b + p; }
    else if (p < 163840) {
      int q = p - 32768, row = q >> 8, col = (q & 255) * 2;
      src = (col < 256) ? (Wih + row * 256 + col) : (Whh + row * 256 + col - 256);
      dst = Wzr_b + q;
    }
    else if (p < 196608) { int q = p - 163840; src = Wih + 512 * 256 + 2 * q; dst = Win_b + q; }
    else if (p < 229376) { int q = p - 196608; src = Whh + 512 * 256 + 2 * q; dst = Whn_b + q; }
    else if (p < 262144) { int q = p - 229376; src = W1 + 2 * q; dst = W1_b + q; }
    else { int q = p - 262144; src = W2 + 2 * q; dst = W2_b + q; }
    dst[0] = bfpack2(src[0], src[1]);
  }
}

// ---------------- inputs -> fp8 xbf, pure coalesced stream ----------------
// 8192 blocks x 256 thr; thread handles 4 slots of (8 floats -> 8 bytes).
__global__ __launch_bounds__(256) void k_xconv(const float* __restrict__ xin,
                                               unsigned char* __restrict__ xbf) {
#pragma unroll
  for (int j = 0; j < 4; ++j) {
    int flat = blockIdx.x * 1024 + j * 256 + threadIdx.x;
    const float4* src = (const float4*)(xin + (size_t)flat * 8);
    float4 v0 = src[0], v1 = src[1];
    uint2 o;
    o.x = f8q(v0.x) | (f8q(v0.y) << 8) | (f8q(v0.z) << 16) | (f8q(v0.w) << 24);
    o.y = f8q(v1.x) | (f8q(v1.y) << 8) | (f8q(v1.z) << 16) | (f8q(v1.w) << 24);
    ((uint2*)xbf)[flat] = o;
  }
}

// ---------------- slots = mu + sigma*noise; q' = LN(slots)@WqkT + bqk (UNSCALED) ----
__global__ __launch_bounds__(512) void k_qk0(const float* __restrict__ noise,
                                             const float* __restrict__ s_mu,
                                             const float* __restrict__ s_sg,
                                             const float* __restrict__ gsl,
                                             const float* __restrict__ bsl,
                                             const unsigned short* __restrict__ Wqk_b,
                                             const float* __restrict__ bqk,
                                             float* __restrict__ slots,
                                             float* __restrict__ qk) {
  __shared__ __align__(16) unsigned short lnb[16 * 264];
  const int tid = threadIdx.x, bb = blockIdx.x;
  const int lane = tid & 63, wave = tid >> 6;
  const int m16 = lane & 15, quad = lane >> 4;
  const int row = tid >> 5, l32 = tid & 31, d0 = l32 * 8;
  {
    const int grow = bb * 16 + row;            // = b*8 + s
    const int sidx = (grow & 7) * 256 + d0;
    const float* np = noise + (size_t)grow * 256 + d0;
    float4 n0 = *(const float4*)np, n1 = *(const float4*)(np + 4);
    float4 m0 = *(const float4*)(s_mu + sidx), m1 = *(const float4*)(s_mu + sidx + 4);
    float4 g0 = *(const float4*)(s_sg + sidx), g1 = *(const float4*)(s_sg + sidx + 4);
    float x[8] = {m0.x + g0.x * n0.x, m0.y + g0.y * n0.y,
                  m0.z + g0.z * n0.z, m0.w + g0.w * n0.w,
                  m1.x + g1.x * n1.x, m1.y + g1.y * n1.y,
                  m1.z + g1.z * n1.z, m1.w + g1.w * n1.w};
    float* sp_ = slots + (size_t)grow * 256 + d0;
    float4 o0, o1;
    o0.x = x[0]; o0.y = x[1]; o0.z = x[2]; o0.w = x[3];
    o1.x = x[4]; o1.y = x[5]; o1.z = x[6]; o1.w = x[7];
    *(float4*)sp_ = o0; *(float4*)(sp_ + 4) = o1;
    ln_row8(x, gsl, bsl, d0, lnb + row * 264 + d0);
  }
  __syncthreads();
  short8 a8[8];
  load_af<8>(a8, lnb, 264, m16, quad);
#pragma unroll
  for (int i = 0; i < 2; ++i) {
    int t = wave + 8 * i;
    f32x4 acc = gemm_tile<8>(a8, Wqk_b + (size_t)(t * 16 + m16) * 256 + quad * 8,
                             bqk[t * 16 + m16]);
#pragma unroll
    for (int r = 0; r < 4; ++r)
      qk[(size_t)(bb * 16 + quad * 4 + r) * 256 + t * 16 + m16] = acc[r];
  }
}

// ---------------- fp8 MFMA attention pass ----------------
// Per 64-row chunk (4/block): stage xr (row-major dwords) + xt (byte-transposed
// [d/4][n] dwords) -> bar -> phase A (fp8 MFMA, B-frag = b64 from xr rows; P fp8
// into pp[s][n]) -> bar -> phase B (A-frag = byte-extract from xt via v_perm,
// B-frag = b64 from pp) -> bar.
__global__ __launch_bounds__(256) void k_attn(const unsigned char* __restrict__ xbf,
                                              const float* __restrict__ qk,
                                              float* __restrict__ pl,
                                              float* __restrict__ pu) {
  __shared__ __align__(16) unsigned xr[64 * 68];        // row-major: [n][68 dwords]
  __shared__ __align__(16) unsigned xt[64 * 68];        // transposed: [d>>2][68]
  __shared__ __align__(16) unsigned char pp[16 * 72];   // P[s][n] bytes
  __shared__ __align__(16) float lred[4][16];
  const int tid = threadIdx.x;
  const int lane = tid & 63, wave = tid >> 6;
  const int m16 = lane & 15, quad = lane >> 4;
  const int c = blockIdx.x, b = blockIdx.y;
  const int pb = (b * CH + c) * 8;
  const size_t row0 = (size_t)b * Nn + (size_t)c * 256;

  // q A-frags fp8: lane holds q[s=m16][k=quad*8+j]; s>=8 -> zero
  LL aq[8];
  {
    const float* qrow = qk + (size_t)(b * 8 + (m16 & 7)) * 256 + quad * 8;
#pragma unroll
    for (int kk = 0; kk < 8; ++kk) {
      float4 q0 = *(const float4*)(qrow + kk * 32);
      float4 q1 = *(const float4*)(qrow + kk * 32 + 4);
      unsigned lo = f8q(q0.x) | (f8q(q0.y) << 8) | (f8q(q0.z) << 16) | (f8q(q0.w) << 24);
      unsigned hi = f8q(q1.x) | (f8q(q1.y) << 8) | (f8q(q1.z) << 16) | (f8q(q1.w) << 24);
      if (m16 >= 8) { lo = 0u; hi = 0u; }
      aq[kk].u[0] = lo; aq[kk].u[1] = hi;
    }
  }
  float lacc[4] = {0.f, 0.f, 0.f, 0.f};
  f32x4 acc[4];
#pragma unroll
  for (int t = 0; t < 4; ++t) acc[t] = (f32x4){0.f, 0.f, 0.f, 0.f};
  const int d0w = wave * 64;

  const uint4* xb4 = (const uint4*)xbf;  // 16 granules of 16B per 256B row
  uint4 pr[4];
#pragma unroll
  for (int i = 0; i < 4; ++i) {  // prologue: chunk 0
    int flat = i * 256 + tid, n = flat >> 4, od = flat & 15;
    pr[i] = xb4[(row0 + n) * 16 + od];
  }

  for (int ch = 0; ch < 4; ++ch) {
    // ---- stage pr -> xr (row-major) + xt (transposed) ----
#pragma unroll
    for (int i = 0; i < 4; ++i) {
      int flat = i * 256 + tid, n = flat >> 4, od = flat & 15;
      *(uint4*)(xr + n * 68 + od * 4) = pr[i];
      xt[(od * 4 + 0) * 68 + n] = pr[i].x;
      xt[(od * 4 + 1) * 68 + n] = pr[i].y;
      xt[(od * 4 + 2) * 68 + n] = pr[i].z;
      xt[(od * 4 + 3) * 68 + n] = pr[i].w;
    }
    __syncthreads();
    if (ch + 1 < 4) {  // prefetch next chunk (overlaps A+B)
      const size_t nb = row0 + (size_t)(ch + 1) * 64;
#pragma unroll
      for (int i = 0; i < 4; ++i) {
        int flat = i * 256 + tid, n = flat >> 4, od = flat & 15;
        pr[i] = xb4[(nb + n) * 16 + od];
      }
    }
    // ---- phase A: P = q @ X^T (wave w owns n-tile w); logits*0.0625, exp ----
    {
      const int nt = wave;
      f32x4 pacc = (f32x4){0.f, 0.f, 0.f, 0.f};
      const unsigned* xrr = xr + (nt * 16 + m16) * 68 + quad * 2;
#pragma unroll
      for (int kk = 0; kk < 8; ++kk) {
        LL bf;
        bf.l = *(const long long*)(xrr + kk * 8);
        pacc = __builtin_amdgcn_mfma_f32_16x16x32_fp8_fp8(aq[kk].l, bf.l, pacc, 0, 0, 0);
      }
      const int n = nt * 16 + m16;
#pragma unroll
      for (int r = 0; r < 4; ++r) {
        float p = __expf(pacc[r] * 0.0625f);  // |logit| small: no max-shift needed
        lacc[r] += p;
        pp[(quad * 4 + r) * 72 + n] = (unsigned char)f8q(p);
      }
    }
    __syncthreads();
    // ---- phase B: U^T += X^T @ P (wave owns 64 d-cols; 2 n-halves) ----
    const unsigned bsel = (m16 & 3) | (((m16 & 3) + 4) << 8);
#pragma unroll
    for (int nh = 0; nh < 2; ++nh) {
      LL bp;
      bp.l = *(const long long*)(pp + m16 * 72 + nh * 32 + quad * 8);
#pragma unroll
      for (int t = 0; t < 4; ++t) {
        int dq = (d0w + t * 16 + m16) >> 2;  // = wave*16 + t*4 + (m16>>2)
        const unsigned* xtp = xt + dq * 68 + nh * 32 + quad * 8;
        uint4 w0 = *(const uint4*)xtp;
        uint4 w1 = *(const uint4*)(xtp + 4);
        unsigned e0 = __builtin_amdgcn_perm(w0.y, w0.x, bsel);
        unsigned e1 = __builtin_amdgcn_perm(w0.w, w0.z, bsel);
        unsigned e2 = __builtin_amdgcn_perm(w1.y, w1.x, bsel);
        unsigned e3 = __builtin_amdgcn_perm(w1.w, w1.z, bsel);
        LL af;
        af.u[0] = __builtin_amdgcn_perm(e1, e0, 0x05040100u);
        af.u[1] = __builtin_amdgcn_perm(e3, e2, 0x05040100u);
        acc[t] = __builtin_amdgcn_mfma_f32_16x16x32_fp8_fp8(af.l, bp.l, acc[t], 0, 0, 0);
      }
    }
    __syncthreads();
  }
  if (m16 < 8) {
#pragma unroll
    for (int t = 0; t < 4; ++t)
#pragma unroll
      for (int r = 0; r < 4; ++r)
        pu[(size_t)(pb + m16) * 256 + d0w + t * 16 + quad * 4 + r] = acc[t][r];
  }
#pragma unroll
  for (int r = 0; r < 4; ++r) {
    float v = lacc[r];
    v += __shfl_xor(v, 1); v += __shfl_xor(v, 2);
    v += __shfl_xor(v, 4); v += __shfl_xor(v, 8);
    if (m16 == 0) lred[wave][quad * 4 + r] = v;
  }
  __syncthreads();
  if (tid < 8)
    pl[pb + tid] = lred[0][tid] + lred[1][tid] + lred[2][tid] + lred[3][tid];
}

// ---------------- fused slot update: combine+Wv+GRU+MLP+LN+next-q' ----------------
// 32 blocks x 512 threads; block = 16 rows (2 batches x 8 slots). R7-verbatim
// except step 9 stores UNSCALED q (attn applies /16).
__global__ __launch_bounds__(512) void k_upd(
    const float* __restrict__ pl, const float* __restrict__ pu,
    const unsigned short* __restrict__ Wv_b, const float* __restrict__ bv,
    const unsigned short* __restrict__ Wzr_b, const float* __restrict__ bzr,
    const unsigned short* __restrict__ Win_b, const float* __restrict__ bin,
    const unsigned short* __restrict__ Whn_b, const float* __restrict__ bhn,
    const unsigned short* __restrict__ W1_b, const float* __restrict__ b1,
    const unsigned short* __restrict__ W2_b, const float* __restrict__ b2,
    const float* __restrict__ gml, const float* __restrict__ bml,
    const float* __restrict__ gsl, const float* __restrict__ bsl,
    const unsigned short* __restrict__ Wqk_b, const float* __restrict__ bqk,
    float* __restrict__ slots, float* __restrict__ qk, float* __restrict__ dout) {
  __shared__ __align__(16) unsigned short cat[16 * 520];
  __shared__ __align__(16) float sp[16 * 260];
  __shared__ __align__(16) float s1[16 * 260];
  __shared__ __align__(16) unsigned short lnb[16 * 264];
  const int tid = threadIdx.x, bb = blockIdx.x;
  const int lane = tid & 63, wave = tid >> 6;
  const int m16 = lane & 15, quad = lane >> 4;
  const int row = tid >> 5, l32 = tid & 31, d0 = l32 * 8;
  const int bat = 2 * bb + (row >> 3), sl = row & 7;
  {
    float L = 0.f;
#pragma unroll
    for (int cc = 0; cc < 16; ++cc) L += pl[(bat * 16 + cc) * 8 + sl];
    float li = 1.f / L;
    float a[8] = {0.f, 0.f, 0.f, 0.f, 0.f, 0.f, 0.f, 0.f};
    for (int cc = 0; cc < 16; ++cc) {
      const float* pp_ = pu + ((size_t)(bat * 16 + cc) * 8 + sl) * 256 + d0;
      float4 v0 = *(const float4*)pp_, v1 = *(const float4*)(pp_ + 4);
      a[0] += v0.x; a[1] += v0.y; a[2] += v0.z; a[3] += v0.w;
      a[4] += v1.x; a[5] += v1.y; a[6] += v1.z; a[7] += v1.w;
    }
    uint4 o;
    o.x = bfpack2(a[0] * li, a[1] * li); o.y = bfpack2(a[2] * li, a[3] * li);
    o.z = bfpack2(a[4] * li, a[5] * li); o.w = bfpack2(a[6] * li, a[7] * li);
    *(uint4*)(cat + row * 520 + d0) = o;
    const float* sp_ = slots + (size_t)(bb * 16 + row) * 256 + d0;
    float4 h0 = *(const float4*)sp_, h1 = *(const float4*)(sp_ + 4);
    *(float4*)(sp + row * 260 + d0) = h0;
    *(float4*)(sp + row * 260 + d0 + 4) = h1;
    uint4 hb;
    hb.x = bfpack2(h0.x, h0.y); hb.y = bfpack2(h0.z, h0.w);
    hb.z = bfpack2(h1.x, h1.y); hb.w = bfpack2(h1.z, h1.w);
    *(uint4*)(cat + row * 520 + 256 + d0) = hb;
  }
  __syncthreads();
  short8 afr[16];
  load_af<8>(afr, cat, 520, m16, quad);
  f32x4 accv[2];
#pragma unroll
  for (int i = 0; i < 2; ++i) {
    int t = wave + 8 * i;
    accv[i] = gemm_tile<8>(afr, Wv_b + (size_t)(t * 16 + m16) * 256 + quad * 8,
                           bv[t * 16 + m16]);
  }
  __syncthreads();
#pragma unroll
  for (int i = 0; i < 2; ++i) {
    int t = wave + 8 * i;
#pragma unroll
    for (int r = 0; r < 4; ++r)
      cat[(quad * 4 + r) * 520 + t * 16 + m16] = bf16r(accv[i][r]);
  }
  __syncthreads();
  load_af<16>(afr, cat, 520, m16, quad);
  f32x4 rr[2], zz[2];
#pragma unroll
  for (int i = 0; i < 2; ++i) {
    int t = wave + 8 * i;
    f32x4 ar = gemm_tile<16>(afr, Wzr_b + (size_t)(t * 16 + m16) * 512 + quad * 8,
                             bzr[t * 16 + m16]);
    f32x4 az = gemm_tile<16>(afr, Wzr_b + (size_t)((t + 16) * 16 + m16) * 512 + quad * 8,
                             bzr[(t + 16) * 16 + m16]);
#pragma unroll
    for (int r = 0; r < 4; ++r) { rr[i][r] = sigm(ar[r]); zz[i][r] = sigm(az[r]); }
  }
#pragma unroll
  for (int i = 0; i < 2; ++i) {
    int t = wave + 8 * i, col = t * 16 + m16;
    f32x4 ain = gemm_tile<8>(afr, Win_b + (size_t)(t * 16 + m16) * 256 + quad * 8,
                             bin[col]);
    f32x4 ahn = gemm_tile<8>(afr + 8, Whn_b + (size_t)(t * 16 + m16) * 256 + quad * 8,
                             bhn[col]);
#pragma unroll
    for (int r = 0; r < 4; ++r) {
      int rw = quad * 4 + r;
      float nin = ain[r] + rr[i][r] * ahn[r];
      float nn = 1.f - 2.f / (__expf(2.f * nin) + 1.f);  // tanh
      float hpc = sp[rw * 260 + col];
      s1[rw * 260 + col] = hpc + (1.f - zz[i][r]) * nn + zz[i][r] * hpc;
    }
  }
  __syncthreads();
  {
    const float* s1r = s1 + row * 260 + d0;
    float4 v0 = *(const float4*)s1r, v1 = *(const float4*)(s1r + 4);
    float x[8] = {v0.x, v0.y, v0.z, v0.w, v1.x, v1.y, v1.z, v1.w};
    ln_row8(x, gml, bml, d0, lnb + row * 264 + d0);
  }
  __syncthreads();
  load_af<8>(afr, lnb, 264, m16, quad);
#pragma unroll
  for (int i = 0; i < 2; ++i) {
    int t = wave + 8 * i;
    f32x4 acc = gemm_tile<8>(afr, W1_b + (size_t)(t * 16 + m16) * 256 + quad * 8,
                             b1[t * 16 + m16]);
#pragma unroll
    for (int r = 0; r < 4; ++r)
      cat[(quad * 4 + r) * 520 + t * 16 + m16] = bf16r(fmaxf(acc[r], 0.f));
  }
  __syncthreads();
  load_af<8>(afr, cat, 520, m16, quad);
#pragma unroll
  for (int i = 0; i < 2; ++i) {
    int t = wave + 8 * i;
    f32x4 acc = gemm_tile<8>(afr, W2_b + (size_t)(t * 16 + m16) * 256 + quad * 8,
                             b2[t * 16 + m16]);
#pragma unroll
    for (int r = 0; r < 4; ++r) {
      int rw = quad * 4 + r, col = t * 16 + m16;
      float v = acc[r] + s1[rw * 260 + col];
      size_t gi = (size_t)(bb * 16 + rw) * 256 + col;
      slots[gi] = v;
      if (dout) dout[gi] = v;
      sp[rw * 260 + col] = v;
    }
  }
  __syncthreads();
  {
    const float* spr = sp + row * 260 + d0;
    float4 v0 = *(const float4*)spr, v1 = *(const float4*)(spr + 4);
    float x[8] = {v0.x, v0.y, v0.z, v0.w, v1.x, v1.y, v1.z, v1.w};
    ln_row8(x, gsl, bsl, d0, lnb + row * 264 + d0);
  }
  __syncthreads();
  load_af<8>(afr, lnb, 264, m16, quad);
#pragma unroll
  for (int i = 0; i < 2; ++i) {
    int t = wave + 8 * i;
    f32x4 acc = gemm_tile<8>(afr, Wqk_b + (size_t)(t * 16 + m16) * 256 + quad * 8,
                             bqk[t * 16 + m16]);
#pragma unroll
    for (int r = 0; r < 4; ++r)
      qk[(size_t)(bb * 16 + quad * 4 + r) * 256 + t * 16 + m16] = acc[r];
  }
}

// ---------------- launch ----------------
extern "C" void kernel_launch(void* const* d_in, const int* in_sizes, int n_in,
                              void* d_out, int out_size, void* d_ws, size_t ws_size,
                              hipStream_t stream) {
  const float* inputs = (const float*)d_in[0];
  const float* noise = (const float*)d_in[1];
  const float* s_mu = (const float*)d_in[2];
  const float* s_sg = (const float*)d_in[3];
  const float* Wq = (const float*)d_in[4];
  const float* bq = (const float*)d_in[5];
  const float* Wk = (const float*)d_in[6];
  // d_in[7] = bk: unused (softmax-invariant)
  const float* Wv = (const float*)d_in[8];
  const float* bv = (const float*)d_in[9];
  const float* Wih = (const float*)d_in[10];
  const float* bih = (const float*)d_in[11];
  const float* Whh = (const float*)d_in[12];
  const float* bhh = (const float*)d_in[13];
  const float* W1 = (const float*)d_in[14];
  const float* b1 = (const float*)d_in[15];
  const float* W2 = (const float*)d_in[16];
  const float* b2 = (const float*)d_in[17];
  const float* gsl = (const float*)d_in[18];
  const float* bsl = (const float*)d_in[19];
  const float* gml = (const float*)d_in[20];
  const float* bml = (const float*)d_in[21];
  float* out = (float*)d_out;

  char* wsb = (char*)d_ws;
  unsigned char* xbf = (unsigned char*)wsb;  // fp8 copy of inputs: 64 MiB
  float* fp = (float*)(wsb + (size_t)Bn * Nn * Dd * 2);  // keep layout offset
  float* slots = fp; fp += Bn * Ss * Dd;
  float* qk = fp;    fp += Bn * Ss * Dd;
  float* bqk = fp;   fp += Dd;
  float* pl = fp;    fp += Bn * CH * Ss;
  float* pu = fp;    fp += Bn * CH * Ss * Dd;
  float* bzr = fp;   fp += 512;
  unsigned short* wb = (unsigned short*)fp;
  unsigned short* Wv_b = wb;  wb += 65536;
  unsigned short* Wzr_b = wb; wb += 262144;
  unsigned short* Win_b = wb; wb += 65536;
  unsigned short* Whn_b = wb; wb += 65536;
  unsigned short* W1_b = wb;  wb += 65536;
  unsigned short* W2_b = wb;  wb += 65536;
  unsigned short* Wqk_b = wb; wb += 65536;
  (void)in_sizes; (void)n_in; (void)out_size; (void)ws_size;

  k_xconv<<<dim3(8192), dim3(256), 0, stream>>>(inputs, xbf);
  k_prep<<<dim3(1187), dim3(256), 0, stream>>>(
      Wq, Wk, bq, Wqk_b, bqk, Wv, Wih, Whh, W1, W2, bih, bhh, (unsigned*)Wv_b,
      (unsigned*)Wzr_b, (unsigned*)Win_b, (unsigned*)Whn_b, (unsigned*)W1_b,
      (unsigned*)W2_b, bzr);
  k_qk0<<<dim3(32), dim3(512), 0, stream>>>(noise, s_mu, s_sg, gsl, bsl, Wqk_b, bqk,
                                            slots, qk);
  for (int it = 0; it < 3; ++it) {
    k_attn<<<dim3(CH, Bn), dim3(256), 0, stream>>>(xbf, qk, pl, pu);
    k_upd<<<dim3(32), dim3(512), 0, stream>>>(
        pl, pu, Wv_b, bv, Wzr_b, bzr, Win_b, bih + 512, Whn_b, bhh + 512, W1_b, b1,
        W2_b, b2, gml, bml, gsl, bsl, Wqk_b, bqk, slots, qk, (it == 2) ? out : nullptr);
  }
}